// Round 5
// baseline (435.994 us; speedup 1.0000x reference)
//
#include <hip/hip_runtime.h>
#include <hip/hip_bf16.h>
#include <cstdint>
#include <cstddef>

typedef unsigned short u16;
typedef __attribute__((ext_vector_type(8))) short s8v;    // 8 x bf16 = 4 VGPR
typedef __attribute__((ext_vector_type(4))) float f4v;    // 16x16 MFMA acc
typedef __attribute__((ext_vector_type(16))) float f16v;  // 32x32 MFMA acc
typedef __attribute__((ext_vector_type(8))) u16 u16x8;

#define AS1 __attribute__((address_space(1)))
#define AS3 __attribute__((address_space(3)))

// ---- constants for this problem ----
#define BATCH 16
#define SEQ   1024
#define EMBED 768
#define HEADS 12
#define DH    64
#define MTOT  (BATCH*SEQ)       // 16384

__device__ __forceinline__ u16 f2bf(float f) {      // RNE fp32 -> bf16
    union { float f; uint32_t u; } v; v.f = f;
    uint32_t r = v.u + 0x7fffu + ((v.u >> 16) & 1u);
    return (u16)(r >> 16);
}

__device__ __forceinline__ unsigned pk2bf(float a, float b) {  // lo=a, hi=b
    union { __hip_bfloat162 h; unsigned u; } cv;
    cv.h = __float22bfloat162_rn(make_float2(a, b));
    return cv.u;
}

__device__ __forceinline__ void gll16(const u16* g, u16* l) {
    __builtin_amdgcn_global_load_lds((AS1 void*)g, (AS3 void*)l, 16, 0, 0);
}

// ---------------- pack x: fp32 -> bf16 ----------------
__global__ void k_pack_x(const float* __restrict__ x, u16* __restrict__ xb, int n) {
    int i = (blockIdx.x * 256 + threadIdx.x) * 4;
    if (i + 3 < n) {
        float4 f = *(const float4*)(x + i);
        ushort4 o;
        o.x = f2bf(f.x); o.y = f2bf(f.y); o.z = f2bf(f.z); o.w = f2bf(f.w);
        *(ushort4*)(xb + i) = o;
    }
}

// ---------------- pack weights: transpose + bf16, concat QKV ----------------
// Wq/bq pre-scaled by 0.125 (folds attention 1/sqrt(Dh) into Q proj).
__global__ void k_pack_w(const float* __restrict__ Wq, const float* __restrict__ Wk,
                         const float* __restrict__ Wv, const float* __restrict__ Wo,
                         const float* __restrict__ bq, const float* __restrict__ bk,
                         const float* __restrict__ bv,
                         u16* __restrict__ wqkvT, u16* __restrict__ woT,
                         float* __restrict__ bqkv)
{
    const int NQKV = 2304 * 768;
    const int NO = 768 * 768;
    int t = blockIdx.x * 256 + threadIdx.x;
    if (t < NQKV) {
        int n = t % 2304, k = t / 2304;
        const float* src; int nn; float sc;
        if (n < 768)       { src = Wq; nn = n;        sc = 0.125f; }
        else if (n < 1536) { src = Wk; nn = n - 768;  sc = 1.0f;   }
        else               { src = Wv; nn = n - 1536; sc = 1.0f;   }
        wqkvT[(size_t)n * 768 + k] = f2bf(src[(size_t)k * 768 + nn] * sc);
    } else if (t < NQKV + NO) {
        int t2 = t - NQKV;
        int n = t2 % 768, k = t2 / 768;
        woT[(size_t)n * 768 + k] = f2bf(Wo[(size_t)k * 768 + n]);
    } else if (t < NQKV + NO + 2304) {
        int t3 = t - NQKV - NO;
        bqkv[t3] = (t3 < 768) ? bq[t3] * 0.125f
                 : ((t3 < 1536) ? bk[t3 - 768] : bv[t3 - 1536]);
    }
}

// ---------------- GEMM (m97 structure, unchanged) ----------------
template<int MODE>
__global__ __launch_bounds__(256) void k_gemm(
    const u16* __restrict__ A, const u16* __restrict__ BT,
    const float* __restrict__ bias,
    u16* __restrict__ oq, u16* __restrict__ okk, u16* __restrict__ ov,
    float* __restrict__ of)
{
    __shared__ __attribute__((aligned(16))) u16 As[128 * 32];
    __shared__ __attribute__((aligned(16))) u16 Bs[128 * 32];
    const int tid = threadIdx.x;
    const int m0 = blockIdx.x * 128;
    const int n0 = blockIdx.y * 128;
    const int wv = tid >> 6;
    const int ln = tid & 63;
    const int l15 = ln & 15, quad = ln >> 4;
    const int wm = (wv >> 1) * 64, wn = (wv & 1) * 64;
    const int r = tid >> 2, c8 = (tid & 3) * 8;

    const u16* gA0 = A + (size_t)(m0 + r) * 768 + c8;
    const u16* gA1 = gA0 + 64 * 768;
    const u16* gB0 = BT + (size_t)(n0 + r) * 768 + c8;
    const u16* gB1 = gB0 + 64 * 768;
    u16* lA0 = As + wv * 512;
    u16* lA1 = As + 2048 + wv * 512;
    u16* lB0 = Bs + wv * 512;
    u16* lB1 = Bs + 2048 + wv * 512;

    f4v acc[4][4] = {};

    for (int kt = 0; kt < 24; ++kt) {
        const int ko = kt * 32;
        gll16(gA0 + ko, lA0);
        gll16(gA1 + ko, lA1);
        gll16(gB0 + ko, lB0);
        gll16(gB1 + ko, lB1);
        __syncthreads();
        s8v aF[4], bF[4];
#pragma unroll
        for (int i = 0; i < 4; ++i)
            aF[i] = *(const s8v*)(As + (wm + i * 16 + l15) * 32 + quad * 8);
#pragma unroll
        for (int j = 0; j < 4; ++j)
            bF[j] = *(const s8v*)(Bs + (wn + j * 16 + l15) * 32 + quad * 8);
#pragma unroll
        for (int i = 0; i < 4; ++i)
#pragma unroll
            for (int j = 0; j < 4; ++j)
                acc[i][j] = __builtin_amdgcn_mfma_f32_16x16x32_bf16(aF[i], bF[j], acc[i][j], 0, 0, 0);
        __syncthreads();
    }

#pragma unroll
    for (int j = 0; j < 4; ++j) {
        int n = n0 + wn + j * 16 + l15;
        float bs = bias[n];
        if (MODE == 0) {
            u16* dst; int nn;
            if (n < 768)       { dst = oq;  nn = n; }
            else if (n < 1536) { dst = okk; nn = n - 768; }
            else               { dst = ov;  nn = n - 1536; }
#pragma unroll
            for (int i = 0; i < 4; ++i) {
                int mrow = m0 + wm + i * 16 + quad * 4;
#pragma unroll
                for (int rg = 0; rg < 4; ++rg)
                    dst[(size_t)(mrow + rg) * 768 + nn] = f2bf(acc[i][j][rg] + bs);
            }
        } else {
#pragma unroll
            for (int i = 0; i < 4; ++i) {
                int mrow = m0 + wm + i * 16 + quad * 4;
#pragma unroll
                for (int rg = 0; rg < 4; ++rg)
                    of[(size_t)(mrow + rg) * 768 + n] = acc[i][j][rg] + bs;
            }
        }
    }
}

// ---------------- V transpose: (192,1024,64) -> (192,64,1024) ----------------
__global__ void k_transpose_v(const u16* __restrict__ v, u16* __restrict__ vt) {
    __shared__ __attribute__((aligned(16))) u16 ts[64 * 72];
    int g = blockIdx.x >> 4;
    int l0 = (blockIdx.x & 15) << 6;
    const u16* vg = v + (size_t)g * 65536;
    u16* vtg = vt + (size_t)g * 65536;
    int tid = threadIdx.x;
#pragma unroll
    for (int c = tid; c < 512; c += 256) {
        int l = c >> 3, d0 = (c & 7) * 8;
        *(uint4*)(ts + l * 72 + d0) = *(const uint4*)(vg + (size_t)(l0 + l) * 64 + d0);
    }
    __syncthreads();
#pragma unroll
    for (int c = tid; c < 512; c += 256) {
        int d = c >> 3, lc = (c & 7) * 8;
        u16x8 tv;
#pragma unroll
        for (int i = 0; i < 8; ++i) tv[i] = ts[(lc + i) * 72 + d];
        *(u16x8*)(vtg + (size_t)d * 1024 + l0 + lc) = tv;
    }
}

// ---------------- flash attention: 128-row Q block, 32-row wave stripes ----------------
// 32x32x16 MFMA. KV tile 64. LDS 32 KB -> 4 blocks/CU.
// All tiles use XOR row-swizzle: uniform bank spread for every b128 access.
// A/B frag: m|n = lane&31, k = (lane>>5)*8 + j.
// C/D:      col = lane&31, row = (reg&3) + 8*(reg>>2) + 4*(lane>>5).
#define SW(r_, c_) ( ((r_) << 6) + (((((c_) >> 3) ^ ((r_) & 7)) & 7) << 3) + ((c_) & 7) )

__global__ __launch_bounds__(256, 4) void k_attn(
    const u16* __restrict__ qb, const u16* __restrict__ kb,
    const u16* __restrict__ vt, u16* __restrict__ ctx)
{
    __shared__ __attribute__((aligned(16))) u16 Ks[64 * 64];    // 8 KB
    __shared__ __attribute__((aligned(16))) u16 Vts[64 * 64];   // 8 KB
    __shared__ __attribute__((aligned(16))) u16 U[128 * 64];    // 16 KB: Q, then wave-private P slabs

    const int g = blockIdx.x >> 3;
    const int q0 = (blockIdx.x & 7) << 7;    // 128-row q tile
    const int tid = threadIdx.x, wv = tid >> 6, ln = tid & 63;
    const int l31 = ln & 31, hf = ln >> 5;   // hf selects k-half
    const u16* qg = qb + (size_t)g * 65536;
    const u16* kg = kb + (size_t)g * 65536;
    const u16* vtg = vt + (size_t)g * 65536;

    // stage Q (128 x 64) swizzled into U
#pragma unroll
    for (int i = 0; i < 4; ++i) {
        int t = tid + i * 256;
        int r = t >> 3, cb = (t & 7) << 3;
        *(uint4*)(U + SW(r, cb)) = *(const uint4*)(qg + (size_t)(q0 + r) * 64 + cb);
    }
    __syncthreads();
    s8v aQ[4];
#pragma unroll
    for (int kb2 = 0; kb2 < 4; ++kb2)
        aQ[kb2] = *(const s8v*)(U + SW(wv * 32 + l31, kb2 * 16 + hf * 8));

    f16v o0 = {}, o1 = {};
    float rsum[16];
#pragma unroll
    for (int i = 0; i < 16; ++i) rsum[i] = 0.f;

    for (int jt = 0; jt < 16; ++jt) {
        const int n0 = jt * 64;
        __syncthreads();   // prior iteration's Ks/Vts reads (and prologue Q frag reads) done
#pragma unroll
        for (int i = 0; i < 2; ++i) {
            int t = tid + i * 256;
            int r = t >> 3, cb = (t & 7) << 3;
            *(uint4*)(Ks + SW(r, cb))  = *(const uint4*)(kg + (size_t)(n0 + r) * 64 + cb);
            *(uint4*)(Vts + SW(r, cb)) = *(const uint4*)(vtg + (size_t)r * 1024 + n0 + cb);
        }
        __syncthreads();

        // per kv-half: S = Q K^T (32q x 32kv), exp, P write (wave-private slab of U)
#pragma unroll
        for (int nb = 0; nb < 2; ++nb) {
            f16v s = {};
#pragma unroll
            for (int kb2 = 0; kb2 < 4; ++kb2) {
                s8v bK = *(const s8v*)(Ks + SW(nb * 32 + l31, kb2 * 16 + hf * 8));
                s = __builtin_amdgcn_mfma_f32_32x32x16_bf16(aQ[kb2], bK, s, 0, 0, 0);
            }
            int col = nb * 32 + l31;
#pragma unroll
            for (int reg = 0; reg < 16; reg += 2) {
                float p0 = __expf(s[reg]), p1 = __expf(s[reg + 1]);
                rsum[reg] += p0; rsum[reg + 1] += p1;
                unsigned u = pk2bf(p0, p1);
                int row = wv * 32 + (reg & 3) + ((reg >> 2) << 3) + (hf << 2);
                U[SW(row, col)] = (u16)u;
                U[SW(row + 1, col)] = (u16)(u >> 16);
            }
        }

        // O += P V (wave-private P readback; compiler orders same-wave LDS RAW)
#pragma unroll
        for (int kb2 = 0; kb2 < 4; ++kb2) {
            int co = kb2 * 16 + hf * 8;
            s8v aP = *(const s8v*)(U + SW(wv * 32 + l31, co));
            s8v bV0 = *(const s8v*)(Vts + SW(l31, co));
            s8v bV1 = *(const s8v*)(Vts + SW(32 + l31, co));
            o0 = __builtin_amdgcn_mfma_f32_32x32x16_bf16(aP, bV0, o0, 0, 0, 0);
            o1 = __builtin_amdgcn_mfma_f32_32x32x16_bf16(aP, bV1, o1, 0, 0, 0);
        }
    }

    // reduce row sums across the 32 kv lanes (rows depend only on lane>>5)
#pragma unroll
    for (int reg = 0; reg < 16; ++reg) {
        float v = rsum[reg];
        v += __shfl_xor(v, 1, 64);
        v += __shfl_xor(v, 2, 64);
        v += __shfl_xor(v, 4, 64);
        v += __shfl_xor(v, 8, 64);
        v += __shfl_xor(v, 16, 64);
        rsum[reg] = 1.0f / v;
    }

    // write ctx in (B,N,C) head-interleaved layout
    const int b = g / 12, hd = g % 12;
    u16* cbase = ctx + (size_t)b * 786432 + hd * 64;
#pragma unroll
    for (int nb = 0; nb < 2; ++nb) {
        int d = nb * 32 + l31;
        const f16v& ov = nb ? o1 : o0;
#pragma unroll
        for (int reg = 0; reg < 16; ++reg) {
            int q = q0 + wv * 32 + (reg & 3) + ((reg >> 2) << 3) + (hf << 2);
            cbase[(size_t)q * 768 + d] = f2bf(ov[reg] * rsum[reg]);
        }
    }
}

// ---------------- launcher ----------------
extern "C" void kernel_launch(void* const* d_in, const int* in_sizes, int n_in,
                              void* d_out, int out_size, void* d_ws, size_t ws_size,
                              hipStream_t stream) {
    const float* x  = (const float*)d_in[0];
    const float* Wq = (const float*)d_in[1];
    const float* bq = (const float*)d_in[2];
    const float* Wk = (const float*)d_in[3];
    const float* bk = (const float*)d_in[4];
    const float* Wv = (const float*)d_in[5];
    const float* bv = (const float*)d_in[6];
    const float* Wo = (const float*)d_in[7];
    const float* bo = (const float*)d_in[8];
    float* out = (float*)d_out;

    const size_t NTOK = (size_t)MTOT * EMBED;          // 12,582,912
    char* w = (char*)d_ws;
    u16* xb    = (u16*)w;              w += NTOK * 2;  // x bf16; reused as ctx
    u16* qb    = (u16*)w;              w += NTOK * 2;
    u16* kb    = (u16*)w;              w += NTOK * 2;
    u16* vb    = (u16*)w;              w += NTOK * 2;
    u16* vtb   = (u16*)w;              w += NTOK * 2;
    u16* wqkvT = (u16*)w;              w += (size_t)2304 * 768 * 2;
    u16* woT   = (u16*)w;              w += (size_t)768 * 768 * 2;
    float* bqkv = (float*)w;           w += 2304 * 4;
    u16* ctx = xb;                                      // reuse (x dead after GEMM1)

    k_pack_x<<<12288, 256, 0, stream>>>(x, xb, (int)NTOK);
    k_pack_w<<<9225, 256, 0, stream>>>(Wq, Wk, Wv, Wo, bq, bk, bv, wqkvT, woT, bqkv);

    dim3 g1(128, 18);
    k_gemm<0><<<g1, 256, 0, stream>>>(xb, wqkvT, bqkv, qb, kb, vb, nullptr);

    k_transpose_v<<<3072, 256, 0, stream>>>(vb, vtb);
    k_attn<<<1536, 256, 0, stream>>>(qb, kb, vtb, ctx);

    dim3 g2(128, 6);
    k_gemm<1><<<g2, 256, 0, stream>>>(ctx, woT, bo, nullptr, nullptr, nullptr, out);
}

// Round 8
// 366.157 us; speedup vs baseline: 1.1907x; 1.1907x over previous
//
#include <hip/hip_runtime.h>
#include <hip/hip_bf16.h>
#include <cstdint>
#include <cstddef>

typedef unsigned short u16;
typedef __attribute__((ext_vector_type(8))) short s8v;    // 8 x bf16 = 4 VGPR
typedef __attribute__((ext_vector_type(4))) float f4v;    // 16x16 MFMA acc
typedef __attribute__((ext_vector_type(8))) u16 u16x8;

#define AS1 __attribute__((address_space(1)))
#define AS3 __attribute__((address_space(3)))

// ---- constants ----
#define BATCH 16
#define SEQ   1024
#define EMBED 768
#define HEADS 12
#define DH    64
#define MTOT  (BATCH*SEQ)       // 16384

__device__ __forceinline__ u16 f2bf(float f) {      // RNE fp32 -> bf16
    union { float f; uint32_t u; } v; v.f = f;
    uint32_t r = v.u + 0x7fffu + ((v.u >> 16) & 1u);
    return (u16)(r >> 16);
}

__device__ __forceinline__ void gll16(const u16* g, u16* l) {
    __builtin_amdgcn_global_load_lds((AS1 void*)g, (AS3 void*)l, 16, 0, 0);
}

// ---------------- fused pack: x -> bf16; weights transpose+bf16; biases ----------------
// Wq/bq pre-scaled by 0.125 (folds attention 1/sqrt(Dh) into Q proj).
#define XBLOCKS 12288
__global__ void k_pack(const float* __restrict__ x, u16* __restrict__ xb, int nx,
                       const float* __restrict__ Wq, const float* __restrict__ Wk,
                       const float* __restrict__ Wv, const float* __restrict__ Wo,
                       const float* __restrict__ bq, const float* __restrict__ bk,
                       const float* __restrict__ bv,
                       u16* __restrict__ wqkvT, u16* __restrict__ woT,
                       float* __restrict__ bqkv)
{
    if (blockIdx.x < XBLOCKS) {
        int i = (blockIdx.x * 256 + threadIdx.x) * 4;
        if (i + 3 < nx) {
            float4 f = *(const float4*)(x + i);
            ushort4 o;
            o.x = f2bf(f.x); o.y = f2bf(f.y); o.z = f2bf(f.z); o.w = f2bf(f.w);
            *(ushort4*)(xb + i) = o;
        }
        return;
    }
    const int NQKV = 2304 * 768;
    const int NO = 768 * 768;
    int t = (blockIdx.x - XBLOCKS) * 256 + threadIdx.x;
    if (t < NQKV) {
        int n = t % 2304, k = t / 2304;
        const float* src; int nn; float sc;
        if (n < 768)       { src = Wq; nn = n;        sc = 0.125f; }
        else if (n < 1536) { src = Wk; nn = n - 768;  sc = 1.0f;   }
        else               { src = Wv; nn = n - 1536; sc = 1.0f;   }
        wqkvT[(size_t)n * 768 + k] = f2bf(src[(size_t)k * 768 + nn] * sc);
    } else if (t < NQKV + NO) {
        int t2 = t - NQKV;
        int n = t2 % 768, k = t2 / 768;
        woT[(size_t)n * 768 + k] = f2bf(Wo[(size_t)k * 768 + n]);
    } else if (t < NQKV + NO + 2304) {
        int t3 = t - NQKV - NO;
        bqkv[t3] = (t3 < 768) ? bq[t3] * 0.125f
                 : ((t3 < 1536) ? bk[t3 - 768] : bv[t3 - 1536]);
    }
}

// ---------------- GEMM: C[M x N] = A[M x 768] * BT[N x 768]^T + bias ----------------
// 128x128 tile, BK=32, 256 thr (4 waves 2x2), wave tile 64x64 = 4x4 MFMA 16x16x32.
// MODE 0: N=2304, split cols into q/k/v bf16 buffers (round-5 verified epilogue).
// MODE 1: N=768, fp32 out.
// NOTE: do NOT fuse the V transpose here. The reference's reshape-bug view is a
// flat reinterpretation: group g = b*12 + (12*T + nv/64)>>10, l = (12*T + nv/64)&1023
// — token rows scatter with l-stride 12, not expressible coalesced from this tile.
template<int MODE>
__global__ __launch_bounds__(256) void k_gemm(
    const u16* __restrict__ A, const u16* __restrict__ BT,
    const float* __restrict__ bias,
    u16* __restrict__ oq, u16* __restrict__ okk, u16* __restrict__ ov,
    float* __restrict__ of)
{
    __shared__ __attribute__((aligned(16))) u16 As[128 * 32];
    __shared__ __attribute__((aligned(16))) u16 Bs[128 * 32];
    const int tid = threadIdx.x;
    const int m0 = blockIdx.x * 128;
    const int n0 = blockIdx.y * 128;
    const int wv = tid >> 6;
    const int ln = tid & 63;
    const int l15 = ln & 15, quad = ln >> 4;
    const int wm = (wv >> 1) * 64, wn = (wv & 1) * 64;
    const int r = tid >> 2, c8 = (tid & 3) * 8;

    const u16* gA0 = A + (size_t)(m0 + r) * 768 + c8;
    const u16* gA1 = gA0 + 64 * 768;
    const u16* gB0 = BT + (size_t)(n0 + r) * 768 + c8;
    const u16* gB1 = gB0 + 64 * 768;
    u16* lA0 = As + wv * 512;
    u16* lA1 = As + 2048 + wv * 512;
    u16* lB0 = Bs + wv * 512;
    u16* lB1 = Bs + 2048 + wv * 512;

    f4v acc[4][4] = {};

    for (int kt = 0; kt < 24; ++kt) {
        const int ko = kt * 32;
        gll16(gA0 + ko, lA0);
        gll16(gA1 + ko, lA1);
        gll16(gB0 + ko, lB0);
        gll16(gB1 + ko, lB1);
        __syncthreads();
        s8v aF[4], bF[4];
#pragma unroll
        for (int i = 0; i < 4; ++i)
            aF[i] = *(const s8v*)(As + (wm + i * 16 + l15) * 32 + quad * 8);
#pragma unroll
        for (int j = 0; j < 4; ++j)
            bF[j] = *(const s8v*)(Bs + (wn + j * 16 + l15) * 32 + quad * 8);
#pragma unroll
        for (int i = 0; i < 4; ++i)
#pragma unroll
            for (int j = 0; j < 4; ++j)
                acc[i][j] = __builtin_amdgcn_mfma_f32_16x16x32_bf16(aF[i], bF[j], acc[i][j], 0, 0, 0);
        __syncthreads();
    }

    // epilogue: C/D layout col = l15, row = quad*4 + reg (round-5 verified)
#pragma unroll
    for (int j = 0; j < 4; ++j) {
        int n = n0 + wn + j * 16 + l15;
        float bs = bias[n];
        if (MODE == 0) {
            u16* dst; int nn;
            if (n < 768)       { dst = oq;  nn = n; }
            else if (n < 1536) { dst = okk; nn = n - 768; }
            else               { dst = ov;  nn = n - 1536; }
#pragma unroll
            for (int i = 0; i < 4; ++i) {
                int mrow = m0 + wm + i * 16 + quad * 4;
#pragma unroll
                for (int rg = 0; rg < 4; ++rg)
                    dst[(size_t)(mrow + rg) * 768 + nn] = f2bf(acc[i][j][rg] + bs);
            }
        } else {
#pragma unroll
            for (int i = 0; i < 4; ++i) {
                int mrow = m0 + wm + i * 16 + quad * 4;
#pragma unroll
                for (int rg = 0; rg < 4; ++rg)
                    of[(size_t)(mrow + rg) * 768 + n] = acc[i][j][rg] + bs;
            }
        }
    }
}

// ---------------- V transpose: (192,1024,64) -> (192,64,1024) ----------------
// Operates on the FLAT v buffer: group g = flat elements [g*65536,(g+1)*65536)
// -- exactly the reference's reshape-bug view. Verified rounds 3-5.
__global__ void k_transpose_v(const u16* __restrict__ v, u16* __restrict__ vt) {
    __shared__ __attribute__((aligned(16))) u16 ts[64 * 80];
    int g = blockIdx.x >> 4;
    int l0 = (blockIdx.x & 15) << 6;
    const u16* vg = v + (size_t)g * 65536;
    u16* vtg = vt + (size_t)g * 65536;
    int tid = threadIdx.x;
#pragma unroll
    for (int c = tid; c < 512; c += 256) {
        int l = c >> 3, d0 = (c & 7) * 8;
        *(uint4*)(ts + l * 80 + d0) = *(const uint4*)(vg + (size_t)(l0 + l) * 64 + d0);
    }
    __syncthreads();
#pragma unroll
    for (int c = tid; c < 512; c += 256) {
        int d = c >> 3, lc = (c & 7) * 8;
        u16x8 tv;
#pragma unroll
        for (int i = 0; i < 8; ++i) tv[i] = ts[(lc + i) * 80 + d];
        *(u16x8*)(vtg + (size_t)d * 1024 + l0 + lc) = tv;
    }
}

// ---------------- flash attention per (group, 64-row q-tile) ----------------
// Round-4 structure (137.5 us) + XOR-swizzled Ks (fixes its bank conflicts).
// q pre-scaled by 1/8; no online max (|s| <~ 8, exp overflow-safe in fp32).
// LDS ~49 KB -> 3 blocks/CU. 2 barriers per KV tile. P round-trip wave-private.
#define KS2(r_, c_) ( ((r_) << 6) + (((((c_) >> 3) ^ ((r_) & 7)) & 7) << 3) + ((c_) & 7) )
#define PS_OFF(q_, c_) ( ((q_) << 7) + ((((((c_) >> 3) ^ ((((q_) >> 2) & 3) << 1)) & 15) << 3) | ((c_) & 7)) )

__global__ __launch_bounds__(256) void k_attn(
    const u16* __restrict__ qb, const u16* __restrict__ kb,
    const u16* __restrict__ vt, u16* __restrict__ ctx)
{
    __shared__ __attribute__((aligned(16))) u16 Ks[128 * 64];    // 16 KB
    __shared__ __attribute__((aligned(16))) u16 Vts[64 * 136];   // 17408 B
    __shared__ __attribute__((aligned(16))) u16 U[64 * 128];     // 16 KB: Qs then Ps

    const int g = blockIdx.x >> 4;
    const int q0 = (blockIdx.x & 15) << 6;
    const int tid = threadIdx.x, wv = tid >> 6;
    const int ln = tid & 63, l15 = ln & 15, quad = ln >> 4;
    const u16* qg = qb + (size_t)g * 65536;
    const u16* kg = kb + (size_t)g * 65536;
    const u16* vtg = vt + (size_t)g * 65536;

    // stage Q tile (64 x 64, stride 72) into U; consumed into regs before Ps reuse
#pragma unroll
    for (int c = tid; c < 512; c += 256) {
        int rr = c >> 3, d0 = (c & 7) * 8;
        *(uint4*)(U + rr * 72 + d0) = *(const uint4*)(qg + (size_t)(q0 + rr) * 64 + d0);
    }
    __syncthreads();
    s8v aQ0 = *(const s8v*)(U + (wv * 16 + l15) * 72 + quad * 8);
    s8v aQ1 = *(const s8v*)(U + (wv * 16 + l15) * 72 + 32 + quad * 8);

    f4v o[4] = {};
    float rsum[4] = {0.f, 0.f, 0.f, 0.f};

    for (int jt = 0; jt < 8; ++jt) {
        const int n0 = jt * 128;
        __syncthreads();   // prior iteration's Ks/Vts reads (and prologue Q reads) done

        // stage K tile 128 x 64, swizzled (manual uint4; 4 per thread)
#pragma unroll
        for (int i = 0; i < 4; ++i) {
            int t = tid + i * 256;
            int rr = t >> 3, cb = (t & 7) << 3;
            *(uint4*)(Ks + KS2(rr, cb)) = *(const uint4*)(kg + (size_t)(n0 + rr) * 64 + cb);
        }
        // stage Vt tile 64 x 128 (stride 136)
#pragma unroll
        for (int c = tid; c < 1024; c += 256) {
            int d = c >> 4, c0 = (c & 15) * 8;
            *(uint4*)(Vts + d * 136 + c0) = *(const uint4*)(vtg + (size_t)d * 1024 + n0 + c0);
        }
        __syncthreads();

        // S = Q K^T (q pre-scaled by 1/8)
        f4v s[8];
#pragma unroll
        for (int ns = 0; ns < 8; ++ns) {
            int rK = ns * 16 + l15;
            s8v b0 = *(const s8v*)(Ks + KS2(rK, quad * 8));
            s8v b1 = *(const s8v*)(Ks + KS2(rK, quad * 8 + 32));
            f4v t = {};
            t = __builtin_amdgcn_mfma_f32_16x16x32_bf16(aQ0, b0, t, 0, 0, 0);
            t = __builtin_amdgcn_mfma_f32_16x16x32_bf16(aQ1, b1, t, 0, 0, 0);
            s[ns] = t;
        }

        // p = exp(s); per-lane partial row sums (reduced once at end)
#pragma unroll
        for (int ns = 0; ns < 8; ++ns)
#pragma unroll
            for (int rg = 0; rg < 4; ++rg) {
                float p = __expf(s[ns][rg]);
                s[ns][rg] = p;
                rsum[rg] += p;
            }

        // P: C-layout regs -> swizzled LDS (wave-private 16 rows; no barrier)
#pragma unroll
        for (int ns = 0; ns < 8; ++ns)
#pragma unroll
            for (int rg = 0; rg < 4; ++rg) {
                int q = wv * 16 + quad * 4 + rg;
                U[PS_OFF(q, ns * 16 + l15)] = f2bf(s[ns][rg]);
            }

        // O += P V
#pragma unroll
        for (int ks = 0; ks < 4; ++ks) {
            int m = wv * 16 + l15;
            int blk = ks * 4 + quad;
            int sw = ((l15 >> 2) & 3) << 1;
            s8v aP = *(const s8v*)(U + (m << 7) + (((blk ^ sw) & 15) << 3));
#pragma unroll
            for (int ds = 0; ds < 4; ++ds) {
                s8v bV = *(const s8v*)(Vts + (ds * 16 + l15) * 136 + ks * 32 + quad * 8);
                o[ds] = __builtin_amdgcn_mfma_f32_16x16x32_bf16(aP, bV, o[ds], 0, 0, 0);
            }
        }
    }

    // reduce row sums across the 16 l15 lanes (rows live on (quad, rg))
#pragma unroll
    for (int rg = 0; rg < 4; ++rg) {
        float v = rsum[rg];
        v += __shfl_xor(v, 1, 64);
        v += __shfl_xor(v, 2, 64);
        v += __shfl_xor(v, 4, 64);
        v += __shfl_xor(v, 8, 64);
        rsum[rg] = v;
    }

    // normalize + write ctx in (B,N,C) head-interleaved layout
    const int b = g / 12, h = g % 12;
    u16* cbase = ctx + (size_t)b * 786432 + h * 64;
#pragma unroll
    for (int rg = 0; rg < 4; ++rg) {
        float inv = 1.0f / rsum[rg];
        int row = q0 + wv * 16 + quad * 4 + rg;
#pragma unroll
        for (int ds = 0; ds < 4; ++ds)
            cbase[(size_t)row * 768 + ds * 16 + l15] = f2bf(o[ds][rg] * inv);
    }
}

// ---------------- launcher ----------------
extern "C" void kernel_launch(void* const* d_in, const int* in_sizes, int n_in,
                              void* d_out, int out_size, void* d_ws, size_t ws_size,
                              hipStream_t stream) {
    const float* x  = (const float*)d_in[0];
    const float* Wq = (const float*)d_in[1];
    const float* bq = (const float*)d_in[2];
    const float* Wk = (const float*)d_in[3];
    const float* bk = (const float*)d_in[4];
    const float* Wv = (const float*)d_in[5];
    const float* bv = (const float*)d_in[6];
    const float* Wo = (const float*)d_in[7];
    const float* bo = (const float*)d_in[8];
    float* out = (float*)d_out;

    const size_t NTOK = (size_t)MTOT * EMBED;          // 12,582,912
    char* w = (char*)d_ws;
    u16* xb    = (u16*)w;              w += NTOK * 2;  // x bf16; reused as ctx
    u16* qb    = (u16*)w;              w += NTOK * 2;
    u16* kb    = (u16*)w;              w += NTOK * 2;
    u16* vb    = (u16*)w;              w += NTOK * 2;
    u16* vtb   = (u16*)w;              w += NTOK * 2;
    u16* wqkvT = (u16*)w;              w += (size_t)2304 * 768 * 2;
    u16* woT   = (u16*)w;              w += (size_t)768 * 768 * 2;
    float* bqkv = (float*)w;           w += 2304 * 4;
    u16* ctx = xb;                                      // reuse (x dead after GEMM1)

    k_pack<<<XBLOCKS + 9225, 256, 0, stream>>>(x, xb, (int)NTOK,
        Wq, Wk, Wv, Wo, bq, bk, bv, wqkvT, woT, bqkv);

    dim3 g1(128, 18);
    k_gemm<0><<<g1, 256, 0, stream>>>(xb, wqkvT, bqkv, qb, kb, vb, nullptr);

    k_transpose_v<<<3072, 256, 0, stream>>>(vb, vtb);
    k_attn<<<3072, 256, 0, stream>>>(qb, kb, vtb, ctx);

    dim3 g2(128, 6);
    k_gemm<1><<<g2, 256, 0, stream>>>(ctx, woT, bo, nullptr, nullptr, nullptr, out);
}